// Round 14
// baseline (85.619 us; speedup 1.0000x reference)
//
#include <hip/hip_runtime.h>
#include <hip/hip_bf16.h>
#include <cstddef>

// MoE gate: B,S,D,E,K = 4,4096,2048,64,2. N = 16384 tokens.
// out layout: dispatch [N][E][K] (2,097,152 f) | combine [N][E][K] | lbl | z
namespace {
constexpr int kD = 2048;
constexpr int kE = 64;
constexpr int kN = 16384;
constexpr size_t kDispatchFloats = (size_t)kN * kE * 2;  // 2,097,152
constexpr size_t kWsplitOff = 1024;  // float offset of W-image region in ws
}

typedef short short8_t __attribute__((ext_vector_type(8)));
typedef float f32x4 __attribute__((ext_vector_type(4)));

// ---------------------------------------------------------------------------
__global__ void zero_ws_kernel(float* __restrict__ ws) {
  ws[threadIdx.x] = 0.0f;  // 256 accumulator slots (129 used)
}

// fp32 -> 3 scaled bf16 splits: x ~= s1 + s2*2^-8 + s3*2^-16 (all normal bf16)
__device__ __forceinline__ void split3(float f, unsigned short& s1,
                                       unsigned short& s2, unsigned short& s3) {
  __hip_bfloat16 h1 = __float2bfloat16(f);
  float r1 = (f - __bfloat162float(h1)) * 256.0f;
  __hip_bfloat16 h2 = __float2bfloat16(r1);
  float r2 = (r1 - __bfloat162float(h2)) * 256.0f;
  __hip_bfloat16 h3 = __float2bfloat16(r2);
  s1 = __builtin_bit_cast(unsigned short, h1);
  s2 = __builtin_bit_cast(unsigned short, h2);
  s3 = __builtin_bit_cast(unsigned short, h3);
}

// 8 floats (2x f32x4) -> one short8 per split (in-register A-fragment convert)
__device__ __forceinline__ void split8(f32x4 a, f32x4 b, short8_t& o1,
                                       short8_t& o2, short8_t& o3) {
  unsigned short s1, s2, s3;
#define SP(v, i, j) \
  split3((v)[i], s1, s2, s3); o1[j]=(short)s1; o2[j]=(short)s2; o3[j]=(short)s3;
  SP(a, 0, 0) SP(a, 1, 1) SP(a, 2, 2) SP(a, 3, 3)
  SP(b, 0, 4) SP(b, 1, 5) SP(b, 2, 6) SP(b, 3, 7)
#undef SP
}

// ---------------------------------------------------------------------------
// Kernel A: pre-split W into the exact swizzled LDS tile image (r12-proven).
// Per (dq,c): [3][64][64]-short tile; [s][row][cs8*8+j] holds
// Wsplit_s[row][(cs8 ^ (row&7))*8 + j] so a linear DMA reproduces the tile.
__global__ __launch_bounds__(256)
void split_w_kernel(const float* __restrict__ W, unsigned short* __restrict__ img) {
  const int t   = blockIdx.x * 256 + threadIdx.x;  // 0..16383
  const int dq  = t >> 12;
  const int c   = (t >> 9) & 7;
  const int row = (t >> 3) & 63;
  const int cs8 = t & 7;
  const int co  = cs8 ^ (row & 7);
  const float* src = W + (size_t)row * kD + dq * 512 + c * 64 + co * 8;
  const float4 v0 = *reinterpret_cast<const float4*>(src);
  const float4 v1 = *reinterpret_cast<const float4*>(src + 4);
  short8_t o1, o2, o3;
  unsigned short s1, s2, s3;
  split3(v0.x, s1, s2, s3); o1[0]=(short)s1; o2[0]=(short)s2; o3[0]=(short)s3;
  split3(v0.y, s1, s2, s3); o1[1]=(short)s1; o2[1]=(short)s2; o3[1]=(short)s3;
  split3(v0.z, s1, s2, s3); o1[2]=(short)s1; o2[2]=(short)s2; o3[2]=(short)s3;
  split3(v0.w, s1, s2, s3); o1[3]=(short)s1; o2[3]=(short)s2; o3[3]=(short)s3;
  split3(v1.x, s1, s2, s3); o1[4]=(short)s1; o2[4]=(short)s2; o3[4]=(short)s3;
  split3(v1.y, s1, s2, s3); o1[5]=(short)s1; o2[5]=(short)s2; o3[5]=(short)s3;
  split3(v1.z, s1, s2, s3); o1[6]=(short)s1; o2[6]=(short)s2; o3[6]=(short)s3;
  split3(v1.w, s1, s2, s3); o1[7]=(short)s1; o2[7]=(short)s2; o3[7]=(short)s3;
  unsigned short* dst = img + (size_t)(dq * 8 + c) * 12288 + row * 64 + cs8 * 8;
  *reinterpret_cast<short8_t*>(dst + 0 * 4096) = o1;
  *reinterpret_cast<short8_t*>(dst + 1 * 4096) = o2;
  *reinterpret_cast<short8_t*>(dst + 2 * 4096) = o3;
}

// ---------------------------------------------------------------------------
// Kernel B: partial logits. Grid 1024 = 256 tiles x 4 K-quarters; 256 thr =
// 4 waves = (token-half wr x expert-half wc); BK=64, 8 chunks.
//   x: NEVER in LDS. A-fragments are lane-private (row=l&15, k=(l>>4)*8..+8,
//      contiguous fp32) -> 8 float4 global loads per chunk, prefetched one
//      full chunk ahead, converted in-register (split8) at point of use.
//   W: double-buffered 2x24KB LDS, DMA'd from the pre-swizzled image while
//      the current chunk computes; counted vmcnt(8) drains only the 6 DMA
//      loads -- the 8 x-prefetch loads stay in flight across the barrier.
// One barrier per chunk. Numerics bit-identical to r8 (absmax 0.0).
__global__ __launch_bounds__(256, 3)
void logits_kernel(const float* __restrict__ x,
                   const unsigned short* __restrict__ wimg,
                   float* __restrict__ out) {
  __shared__ unsigned short wt[2][3][64][64];  // W tiles, 48 KB dbuf

  const int tid  = threadIdx.x;
  const int lane = tid & 63;
  const int wv   = __builtin_amdgcn_readfirstlane(tid >> 6);
  const int wr   = wv >> 1;        // token half
  const int wc   = wv & 1;         // expert half
  const int tile = blockIdx.x & 255;
  const int dq   = blockIdx.x >> 8;
  const int lrow = lane & 15;
  const int lk   = lane >> 4;

  // per-lane A-fragment base pointers for the two mt rows
  const float* __restrict__ xb[2];
  xb[0] = x + (size_t)(tile * 64 + wr * 32 + lrow) * kD + dq * 512 + lk * 8;
  xb[1] = xb[0] + (size_t)16 * kD;

  const unsigned short* __restrict__ wbase =
      wimg + (size_t)dq * 8 * 12288 + tid * 8;

  f32x4 acc0[2][2], acc1[2][2], acc2[2][2];
  const f32x4 z4 = {0.0f, 0.0f, 0.0f, 0.0f};
#pragma unroll
  for (int a = 0; a < 2; ++a)
#pragma unroll
    for (int b = 0; b < 2; ++b) { acc0[a][b] = z4; acc1[a][b] = z4; acc2[a][b] = z4; }

  f32x4 xc[8], xn[8];  // [mt*4 + ks*2 + j], all statically indexed

  // prologue: DMA chunk 0 -> buf 0; x chunk 0 -> xc
  {
    unsigned short* dst = &wt[0][0][0][0];
#pragma unroll
    for (int i = 0; i < 6; ++i)
      __builtin_amdgcn_global_load_lds(
          (const __attribute__((address_space(1))) void*)(wbase + i * 2048),
          (__attribute__((address_space(3))) void*)(dst + i * 2048 + wv * 512),
          16, 0, 0);
#pragma unroll
    for (int mt = 0; mt < 2; ++mt)
#pragma unroll
      for (int ks = 0; ks < 2; ++ks)
#pragma unroll
        for (int j = 0; j < 2; ++j)
          xc[mt * 4 + ks * 2 + j] =
              *reinterpret_cast<const f32x4*>(xb[mt] + ks * 32 + j * 4);
    __builtin_amdgcn_sched_barrier(0);
    asm volatile("s_waitcnt vmcnt(8)" ::: "memory");  // DMAs done; x in flight
    __builtin_amdgcn_s_barrier();
  }

#pragma unroll 2
  for (int c = 0; c < 8; ++c) {
    const int cb = c & 1, cn = (c + 1) & 7;
    // 1. DMA next W tile into the other buffer (free: last read 2 iters ago)
    {
      unsigned short* dst = &wt[cb ^ 1][0][0][0];
      const unsigned short* src = wbase + (size_t)cn * 12288;
#pragma unroll
      for (int i = 0; i < 6; ++i)
        __builtin_amdgcn_global_load_lds(
            (const __attribute__((address_space(1))) void*)(src + i * 2048),
            (__attribute__((address_space(3))) void*)(dst + i * 2048 + wv * 512),
            16, 0, 0);
    }
    // 2. prefetch next x chunk (wraps on last iter -> uniform vmcnt)
#pragma unroll
    for (int mt = 0; mt < 2; ++mt)
#pragma unroll
      for (int ks = 0; ks < 2; ++ks)
#pragma unroll
        for (int j = 0; j < 2; ++j)
          xn[mt * 4 + ks * 2 + j] = *reinterpret_cast<const f32x4*>(
              xb[mt] + cn * 64 + ks * 32 + j * 4);
    __builtin_amdgcn_sched_barrier(0);  // pin: all loads issued before compute
    // 3. compute chunk c: B from LDS buf cb, A converted in-register from xc
#pragma unroll
    for (int ks = 0; ks < 2; ++ks) {
      const int kc = ks * 4 + lk;
      short8_t b1[2], b2[2], b3[2];
#pragma unroll
      for (int nt = 0; nt < 2; ++nt) {
        const int e = wc * 32 + nt * 16 + lrow;
        const int cw = (kc ^ (e & 7)) * 8;
        b1[nt] = *reinterpret_cast<const short8_t*>(&wt[cb][0][e][cw]);
        b2[nt] = *reinterpret_cast<const short8_t*>(&wt[cb][1][e][cw]);
        b3[nt] = *reinterpret_cast<const short8_t*>(&wt[cb][2][e][cw]);
      }
#pragma unroll
      for (int mt = 0; mt < 2; ++mt) {
        short8_t a1, a2, a3;
        split8(xc[mt * 4 + ks * 2], xc[mt * 4 + ks * 2 + 1], a1, a2, a3);
#pragma unroll
        for (int nt = 0; nt < 2; ++nt) {
          acc0[mt][nt] = __builtin_amdgcn_mfma_f32_16x16x32_bf16(a1, b1[nt], acc0[mt][nt], 0, 0, 0);
          acc1[mt][nt] = __builtin_amdgcn_mfma_f32_16x16x32_bf16(a1, b2[nt], acc1[mt][nt], 0, 0, 0);
          acc1[mt][nt] = __builtin_amdgcn_mfma_f32_16x16x32_bf16(a2, b1[nt], acc1[mt][nt], 0, 0, 0);
          acc2[mt][nt] = __builtin_amdgcn_mfma_f32_16x16x32_bf16(a1, b3[nt], acc2[mt][nt], 0, 0, 0);
          acc2[mt][nt] = __builtin_amdgcn_mfma_f32_16x16x32_bf16(a3, b1[nt], acc2[mt][nt], 0, 0, 0);
          acc2[mt][nt] = __builtin_amdgcn_mfma_f32_16x16x32_bf16(a2, b2[nt], acc2[mt][nt], 0, 0, 0);
        }
      }
    }
    __builtin_amdgcn_sched_barrier(0);
    // 4. drain the 6 DMAs only; the 8 x-loads stay in flight across barrier
    asm volatile("s_waitcnt vmcnt(8)" ::: "memory");
    __builtin_amdgcn_s_barrier();
#pragma unroll
    for (int i = 0; i < 8; ++i) xc[i] = xn[i];  // renamed away by unroll-2
  }

  // epilogue: L = acc0 + acc1*2^-8 + acc2*2^-16 -> token's own partial slots
  const float k8 = 1.0f / 256.0f, k16 = 1.0f / 65536.0f;
  float* __restrict__ base = out + ((dq < 2) ? (size_t)0 : kDispatchFloats);
#pragma unroll
  for (int mt = 0; mt < 2; ++mt)
#pragma unroll
    for (int r = 0; r < 4; ++r) {
      const int trow = wr * 32 + mt * 16 + lk * 4 + r;  // C row = (lane>>4)*4+r
      const size_t n = (size_t)tile * 64 + trow;
      float* __restrict__ dst =
          base + n * 128 + (dq & 1) * 64 + wc * 32 + lrow;  // C col = lane&15
#pragma unroll
      for (int nt = 0; nt < 2; ++nt)
        dst[nt * 16] = acc0[mt][nt][r] + acc1[mt][nt][r] * k8 + acc2[mt][nt][r] * k16;
    }
}

// ---------------------------------------------------------------------------
// Kernel C: sum 4 partials -> logits, softmax, top-2, outputs, losses.
__global__ __launch_bounds__(256)
void gate_kernel(float* __restrict__ out, float* __restrict__ ws) {
  __shared__ float lg[64][65];
  __shared__ int ti0[64], ti1[64];
  __shared__ float tv0[64], tv1[64], tz2[64];
  const int tid  = threadIdx.x;
  const int tile = blockIdx.x;

  float* __restrict__ outd = out + (size_t)tile * 8192;
  float* __restrict__ outc = out + kDispatchFloats + (size_t)tile * 8192;
  const float4* __restrict__ d4 = reinterpret_cast<const float4*>(outd);
  const float4* __restrict__ c4 = reinterpret_cast<const float4*>(outc);

  const int tq = tid >> 4, q = tid & 15;
#pragma unroll
  for (int k = 0; k < 4; ++k) {
    const int t = k * 16 + tq;
    const float4 a = d4[t * 32 + q];
    const float4 b = d4[t * 32 + 16 + q];
    const float4 c = c4[t * 32 + q];
    const float4 d = c4[t * 32 + 16 + q];
    lg[t][q * 4 + 0] = a.x + b.x + c.x + d.x;
    lg[t][q * 4 + 1] = a.y + b.y + c.y + d.y;
    lg[t][q * 4 + 2] = a.z + b.z + c.z + d.z;
    lg[t][q * 4 + 3] = a.w + b.w + c.w + d.w;
  }
  __syncthreads();

  if (tid < 64) {
    float v0 = -INFINITY, v1 = -INFINITY;
    int i0 = 0, i1 = 0;
    for (int e = 0; e < kE; ++e) {
      const float l = lg[tid][e];
      if (l > v0) { v1 = v0; i1 = i0; v0 = l; i0 = e; }
      else if (l > v1) { v1 = l; i1 = e; }
    }
    const float m = v0;
    float s = 0.0f;
    for (int e = 0; e < kE; ++e) s += __expf(lg[tid][e] - m);
    const float rs = 1.0f / s;
    float zexp = 0.0f;
    for (int e = 0; e < kE; ++e) zexp += __expf(__expf(lg[tid][e] - m) * rs);
    const float z = logf(zexp);
    ti0[tid] = i0; ti1[tid] = i1;
    tv0[tid] = rs;                    // exp(v0-m)*rs with v0==m
    tv1[tid] = __expf(v1 - m) * rs;
    tz2[tid] = z * z;
  }
  __syncthreads();

  if (tid < kE) {
    float g = 0.0f, cnt = 0.0f;
    for (int t = 0; t < 64; ++t) {
      if (ti0[t] == tid) { g += tv0[t]; cnt += 1.0f; }
      if (ti1[t] == tid) { g += tv1[t]; cnt += 1.0f; }
    }
    atomicAdd(&ws[tid], g);
    atomicAdd(&ws[kE + tid], cnt);
    float z2 = tz2[tid];
    for (int off = 32; off; off >>= 1) z2 += __shfl_down(z2, off);
    if (tid == 0) atomicAdd(&ws[2 * kE], z2);
  }

  {
    const int t = tid >> 2, sub = tid & 3;
    const int i0 = ti0[t], i1 = ti1[t];
    const float v0 = tv0[t], v1 = tv1[t];
    float4* __restrict__ dp = reinterpret_cast<float4*>(outd) + t * 32;
    float4* __restrict__ cp = reinterpret_cast<float4*>(outc) + t * 32;
#pragma unroll
    for (int j = 0; j < 8; ++j) {
      const int qq = sub * 8 + j;
      const int e0 = qq * 2, e1 = qq * 2 + 1;
      const float d0v = (e0 == i0 || e0 == i1) ? 1.0f : 0.0f;
      const float d1v = (e1 == i0 || e1 == i1) ? 1.0f : 0.0f;
      const float c0 = (e0 == i0) ? v0 : ((e0 == i1) ? v1 : 0.0f);
      const float c1 = (e1 == i0) ? v0 : ((e1 == i1) ? v1 : 0.0f);
      dp[qq] = make_float4(d0v, 0.0f, d1v, 0.0f);
      cp[qq] = make_float4(c0, 0.0f, c1, 0.0f);
    }
  }
}

// ---------------------------------------------------------------------------
__global__ void finalize_kernel(const float* __restrict__ ws,
                                float* __restrict__ out) {
  const int e = threadIdx.x;  // 64 threads
  float prod = ws[e] * ws[kE + e];
  for (int off = 32; off; off >>= 1) prod += __shfl_down(prod, off);
  if (e == 0) {
    const size_t base = kDispatchFloats * 2;
    const float invN = 1.0f / (float)kN;
    out[base]     = prod * ((float)kE * invN * invN);  // load_balancing_loss
    out[base + 1] = ws[2 * kE] * invN;                 // router_z_loss
  }
}

// ---------------------------------------------------------------------------
extern "C" void kernel_launch(void* const* d_in, const int* in_sizes, int n_in,
                              void* d_out, int out_size, void* d_ws,
                              size_t ws_size, hipStream_t stream) {
  const float* x = (const float*)d_in[0];  // [4,4096,2048] fp32
  const float* W = (const float*)d_in[1];  // [64,2048] fp32
  float* out = (float*)d_out;
  float* ws = (float*)d_ws;
  unsigned short* wimg = (unsigned short*)(ws + kWsplitOff);

  zero_ws_kernel<<<1, 256, 0, stream>>>(ws);
  split_w_kernel<<<64, 256, 0, stream>>>(W, wimg);
  logits_kernel<<<1024, 256, 0, stream>>>(x, wimg, out);
  gate_kernel<<<256, 256, 0, stream>>>(out, ws);
  finalize_kernel<<<1, kE, 0, stream>>>(ws, out);
}